// Round 3
// baseline (36.409 us; speedup 1.0000x reference)
//
#include <hip/hip_runtime.h>

// NormalizedBoxCenterEncoder  B=32, N=100000, M=500  (all f32 + int32 matches)
// d_out: targets (B,N,4) then masks (B,N,4), flat f32.

#define BB 32
#define NN 100000
#define MM 500
#define TOTAL (BB * NN)          // 3,200,000 — divisible by 512
#define ITEMS_PER_BLOCK 512      // 256 threads x 2 wave-stride items

// native clang vector type — required by __builtin_nontemporal_*
typedef float f32x4 __attribute__((ext_vector_type(4)));

__global__ __launch_bounds__(256) void nbce_kernel(
    const float*  __restrict__ samples,
    const int*    __restrict__ matches,
    const f32x4*  __restrict__ anchors,
    const f32x4*  __restrict__ refs,
    f32x4*        __restrict__ targets,
    f32x4*        __restrict__ masks)
{
    int base = blockIdx.x * ITEMS_PER_BLOCK + threadIdx.x;

#pragma unroll
    for (int u = 0; u < 2; ++u) {
        int i = base + u * 256;               // grid covers TOTAL exactly

        int b = i / NN;                       // magic-mul
        int idx = matches[i];                 // streaming read (coalesced 4B)
        idx = idx < 0 ? 0 : idx;              // jnp.clip(matches, 0)

        // refs: 256 KB table, keep CACHED — the random 16B gather must hit
        // L1/L2.
        f32x4 rb = refs[b * MM + idx];

        // streaming, read-once → nontemporal to avoid evicting refs from L2
        f32x4 ab = __builtin_nontemporal_load(&anchors[i]);
        float s  = __builtin_nontemporal_load(&samples[i]);

        float aw = ab.z - ab.x;
        float ah = ab.w - ab.y;
        float ax = ab.x + aw * 0.5f;
        float ay = ab.y + ah * 0.5f;

        float gw = rb.z - rb.x;
        float gh = rb.w - rb.y;
        float gx = rb.x + gw * 0.5f;
        float gy = rb.y + gh * 0.5f;

        // MEANS = 0; STDS = (.1,.1,.2,.2) -> x10, x10, x5, x5
        float t0 = ((gx - ax) / aw) * 10.0f;
        float t1 = ((gy - ay) / ah) * 10.0f;
        float t2 = __logf(gw / aw) * 5.0f;
        float t3 = __logf(gh / ah) * 5.0f;

        bool  pos = s > 0.5f;                 // samples are +-1
        float m   = pos ? 1.0f : 0.0f;

        f32x4 tv;
        tv.x = pos ? t0 : 0.0f;
        tv.y = pos ? t1 : 0.0f;
        tv.z = pos ? t2 : 0.0f;
        tv.w = pos ? t3 : 0.0f;
        f32x4 mv = {m, m, m, m};

        // write-once streams → nontemporal stores (full-line coalesced)
        __builtin_nontemporal_store(tv, &targets[i]);
        __builtin_nontemporal_store(mv, &masks[i]);
    }
}

extern "C" void kernel_launch(void* const* d_in, const int* in_sizes, int n_in,
                              void* d_out, int out_size, void* d_ws, size_t ws_size,
                              hipStream_t stream)
{
    const float* samples = (const float*)d_in[0];
    const int*   matches = (const int*)d_in[1];
    const f32x4* anchors = (const f32x4*)d_in[2];
    const f32x4* refs    = (const f32x4*)d_in[3];

    float* out = (float*)d_out;
    f32x4* targets = (f32x4*)out;                         // B*N*4 floats
    f32x4* masks   = (f32x4*)(out + (size_t)TOTAL * 4);   // next B*N*4 floats

    int grid = TOTAL / ITEMS_PER_BLOCK;   // 6250 blocks, covers exactly
    nbce_kernel<<<grid, 256, 0, stream>>>(samples, matches, anchors, refs,
                                          targets, masks);
}

// Round 4
// 32.124 us; speedup vs baseline: 1.1334x; 1.1334x over previous
//
#include <hip/hip_runtime.h>

// NormalizedBoxCenterEncoder  B=32, N=100000, M=500  (all f32 + int32 matches)
// d_out: targets (B,N,4) then masks (B,N,4), flat f32.
// R4: R3 structure (2-item wave-stride unroll) with ALL nontemporal hints
// removed — isolates the NT-vs-unroll confound from R3's regression.

#define BB 32
#define NN 100000
#define MM 500
#define TOTAL (BB * NN)          // 3,200,000 — divisible by 512
#define ITEMS_PER_BLOCK 512      // 256 threads x 2 wave-stride items

typedef float f32x4 __attribute__((ext_vector_type(4)));

__global__ __launch_bounds__(256) void nbce_kernel(
    const float*  __restrict__ samples,
    const int*    __restrict__ matches,
    const f32x4*  __restrict__ anchors,
    const f32x4*  __restrict__ refs,
    f32x4*        __restrict__ targets,
    f32x4*        __restrict__ masks)
{
    int base = blockIdx.x * ITEMS_PER_BLOCK + threadIdx.x;

#pragma unroll
    for (int u = 0; u < 2; ++u) {
        int i = base + u * 256;               // grid covers TOTAL exactly

        int b = i / NN;                       // magic-mul
        int idx = matches[i];                 // coalesced 4B
        idx = idx < 0 ? 0 : idx;              // jnp.clip(matches, 0)

        f32x4 rb = refs[b * MM + idx];        // 256 KB table, L1/L2-resident
        f32x4 ab = anchors[i];                // coalesced 16B
        float s  = samples[i];                // coalesced 4B

        float aw = ab.z - ab.x;
        float ah = ab.w - ab.y;
        float ax = ab.x + aw * 0.5f;
        float ay = ab.y + ah * 0.5f;

        float gw = rb.z - rb.x;
        float gh = rb.w - rb.y;
        float gx = rb.x + gw * 0.5f;
        float gy = rb.y + gh * 0.5f;

        // MEANS = 0; STDS = (.1,.1,.2,.2) -> x10, x10, x5, x5
        float t0 = ((gx - ax) / aw) * 10.0f;
        float t1 = ((gy - ay) / ah) * 10.0f;
        float t2 = __logf(gw / aw) * 5.0f;
        float t3 = __logf(gh / ah) * 5.0f;

        bool  pos = s > 0.5f;                 // samples are +-1
        float m   = pos ? 1.0f : 0.0f;

        f32x4 tv;
        tv.x = pos ? t0 : 0.0f;
        tv.y = pos ? t1 : 0.0f;
        tv.z = pos ? t2 : 0.0f;
        tv.w = pos ? t3 : 0.0f;
        f32x4 mv = {m, m, m, m};

        targets[i] = tv;                      // coalesced 16B stores
        masks[i]   = mv;
    }
}

extern "C" void kernel_launch(void* const* d_in, const int* in_sizes, int n_in,
                              void* d_out, int out_size, void* d_ws, size_t ws_size,
                              hipStream_t stream)
{
    const float* samples = (const float*)d_in[0];
    const int*   matches = (const int*)d_in[1];
    const f32x4* anchors = (const f32x4*)d_in[2];
    const f32x4* refs    = (const f32x4*)d_in[3];

    float* out = (float*)d_out;
    f32x4* targets = (f32x4*)out;                         // B*N*4 floats
    f32x4* masks   = (f32x4*)(out + (size_t)TOTAL * 4);   // next B*N*4 floats

    int grid = TOTAL / ITEMS_PER_BLOCK;   // 6250 blocks
    nbce_kernel<<<grid, 256, 0, stream>>>(samples, matches, anchors, refs,
                                          targets, masks);
}